// Round 2
// baseline (485.428 us; speedup 1.0000x reference)
//
#include <hip/hip_runtime.h>
#include <hip/hip_bf16.h>

// SupConLoss fused: logits = text @ image^T (bf16 MFMA), masked two-sided
// logsumexp with fixed shift, softplus-mean -> scalar.
// B = N = 8192, D = 256, NUM_CLASSES = 64, T = 1.
//
// R1: LDS-staged B tiles (global_load_lds w=16, double-buffered), counted
// vmcnt(4) prefetch pipeline, CSPLIT 8->32 for occupancy.

#define B_ROWS 8192
#define N_COLS 8192
#define DIM    256
#define CSPLIT 32                       // grid = (64, 32) = 2048 blocks
#define NTILES ((N_COLS / CSPLIT) / 32) // 8 col-tiles of 32 per block
#define WAVES  4                        // 4 waves x 32 rows = 128 rows/block

typedef __attribute__((ext_vector_type(8)))  short bf16x8;   // 8 bf16 = 4 VGPR
typedef __attribute__((ext_vector_type(16))) float f32x16;   // MFMA 32x32 acc

#if __has_builtin(__builtin_amdgcn_exp2f)
#define EXP2F(x) __builtin_amdgcn_exp2f(x)
#else
#define EXP2F(x) exp2f(x)
#endif
#if __has_builtin(__builtin_amdgcn_logf)
#define LOG2F(x) __builtin_amdgcn_logf(x)
#else
#define LOG2F(x) log2f(x)
#endif

// f32 -> bf16 (RNE), 4 elements/thread
__global__ void cvt_bf16_kernel(const float* __restrict__ in,
                                unsigned short* __restrict__ out, int n4) {
    int i = blockIdx.x * blockDim.x + threadIdx.x;
    if (i >= n4) return;
    float4 v = reinterpret_cast<const float4*>(in)[i];
    union { float f; unsigned u; } c;
    ushort4 o;
    c.f = v.x; o.x = (unsigned short)((c.u + 0x7FFFu + ((c.u >> 16) & 1u)) >> 16);
    c.f = v.y; o.y = (unsigned short)((c.u + 0x7FFFu + ((c.u >> 16) & 1u)) >> 16);
    c.f = v.z; o.z = (unsigned short)((c.u + 0x7FFFu + ((c.u >> 16) & 1u)) >> 16);
    c.f = v.w; o.w = (unsigned short)((c.u + 0x7FFFu + ((c.u >> 16) & 1u)) >> 16);
    reinterpret_cast<ushort4*>(out)[i] = o;
}

// mfma_f32_32x32x16_bf16 layouts (HW-verified; R0 passed with absmax 0.0):
//   A: row = lane&31, k = 8*(lane>>5)+j
//   B: col = lane&31, k = 8*(lane>>5)+j
//   C: col = lane&31, row = (r&3) + 8*(r>>2) + 4*(lane>>5)
//
// LDS tile layout: chunk c in [0,1024) of 16B; c -> (ks2 = c>>5, col = c&31),
// holds B[cb+col][ks2*8 .. ks2*8+8). Staged linearly (chunk c at offset c*16)
// so global_load_lds's wave-uniform-base+lane*16 rule is satisfied; read back
// at ks*1024 + half*512 + ln*16 -> stride-16B across lanes = conflict-free
// ds_read_b128.
__launch_bounds__(256, 3)
__global__ void fused_gemm_lse(const unsigned short* __restrict__ Abf,
                               const unsigned short* __restrict__ Bbf,
                               const int* __restrict__ tlab,
                               const int* __restrict__ itgt,
                               float* __restrict__ gsum_p,
                               float* __restrict__ gsum_n) {
    __shared__ char lds[2 * 16384] __attribute__((aligned(128)));

    const int tid  = threadIdx.x;
    const int lane = tid & 63;
    const int wave = tid >> 6;
    const int half = lane >> 5;
    const int ln   = lane & 31;
    const int rb   = blockIdx.x * (32 * WAVES) + wave * 32;
    const int cb0  = blockIdx.y * (N_COLS / CSPLIT);

    // A fragments for all of K=256: 16 k-steps x 4 VGPR = 64 VGPR.
    bf16x8 afrag[16];
    const bf16x8* arow =
        reinterpret_cast<const bf16x8*>(Abf + (size_t)(rb + ln) * DIM) + half;
#pragma unroll
    for (int ks = 0; ks < 16; ++ks) afrag[ks] = arow[ks * 2];

    // Row classes for the 16 accumulator slots.
    int rowcls[16];
#pragma unroll
    for (int r = 0; r < 16; ++r)
        rowcls[r] = tlab[rb + (r & 3) + 8 * (r >> 2) + 4 * half];

    // Column classes for all NTILES tiles (hoisted so loop vmem = stage only).
    int colcls[NTILES];
#pragma unroll
    for (int t = 0; t < NTILES; ++t)
        colcls[t] = itgt[cb0 + t * 32 + ln];

    float sump[16], sumn[16];
#pragma unroll
    for (int r = 0; r < 16; ++r) { sump[r] = 0.f; sumn[r] = 0.f; }

    // Staging: thread stages chunks c = tid + i*256, i in [0,4).
    //   global byte offset = (cb0 + tile*32 + (c&31))*512 + (c>>5)*16
    //   (c&31) == (tid&31); (c>>5) == (tid>>5) + i*8  ->  base + i*128
    const char* bsrc = (const char*)Bbf + ((size_t)cb0 + (tid & 31)) * 512
                       + (tid >> 5) * 16;
    char* ldsd = lds + tid * 16;

#define STAGE(T, CUR) do {                                                   \
    const char* g_ = bsrc + (size_t)(T) * 16384;                             \
    char* l_ = ldsd + (CUR) * 16384;                                         \
    _Pragma("unroll")                                                        \
    for (int i_ = 0; i_ < 4; ++i_)                                           \
        __builtin_amdgcn_global_load_lds(                                    \
            (const __attribute__((address_space(1))) unsigned int*)(g_ + i_ * 128), \
            (__attribute__((address_space(3))) unsigned int*)(l_ + i_ * 4096),      \
            16, 0, 0);                                                       \
} while (0)

    const float L2E = 1.4426950408889634f;  // log2(e)
    const float C2  = 72.0f;                // fixed shift in log2 domain

    STAGE(0, 0);
    asm volatile("" ::: "memory");  // keep all prologue loads before the loop

#pragma unroll
    for (int t = 0; t < NTILES; ++t) {
        if (t + 1 < NTILES) {
            STAGE(t + 1, (t + 1) & 1);
            // wait current tile's 4 stage loads; keep next tile's 4 in flight
            asm volatile("s_waitcnt vmcnt(4)" ::: "memory");
        } else {
            asm volatile("s_waitcnt vmcnt(0)" ::: "memory");
        }
        __builtin_amdgcn_s_barrier();      // buf[t&1] fully staged by all
        asm volatile("" ::: "memory");

        const char* bbuf = lds + (t & 1) * 16384 + half * 512 + ln * 16;
        f32x16 acc;
#pragma unroll
        for (int r = 0; r < 16; ++r) acc[r] = 0.f;
#pragma unroll
        for (int ks = 0; ks < 16; ++ks) {
            bf16x8 bfrag = *reinterpret_cast<const bf16x8*>(bbuf + ks * 1024);
            acc = __builtin_amdgcn_mfma_f32_32x32x16_bf16(afrag[ks], bfrag, acc,
                                                          0, 0, 0);
        }

        __builtin_amdgcn_s_barrier();      // all waves done reading buf[t&1]
        asm volatile("" ::: "memory");

        // Epilogue VALU: overlaps the in-flight stage of tile t+1.
        const int cc = colcls[t];
#pragma unroll
        for (int r = 0; r < 16; ++r) {
            const float x  = acc[r];
            const bool pos = (rowcls[r] == cc);
            const float e  = EXP2F(__builtin_fmaf(x, pos ? -L2E : L2E, -C2));
            sump[r] += pos ? e : 0.f;
            sumn[r] += pos ? 0.f : e;
        }
    }
#undef STAGE

    // Reduce each row-sum across the 32 lanes of the half-wave, then atomics.
#pragma unroll
    for (int r = 0; r < 16; ++r) {
        float vp = sump[r], vn = sumn[r];
#pragma unroll
        for (int m = 1; m < 32; m <<= 1) {
            vp += __shfl_xor(vp, m, 64);
            vn += __shfl_xor(vn, m, 64);
        }
        if (ln == 0) {
            int row = rb + (r & 3) + 8 * (r >> 2) + 4 * half;
            atomicAdd(&gsum_p[row], vp);
            atomicAdd(&gsum_n[row], vn);
        }
    }
}

// lse_{p,n} = (log2(S) + C2) * ln2 ; loss = mean softplus(lse_p + lse_n)
__global__ void finalize_kernel(const float* __restrict__ gsum_p,
                                const float* __restrict__ gsum_n,
                                float* __restrict__ out) {
    __shared__ float red[1024];
    const float LN2 = 0.6931471805599453f;
    const float C2  = 72.0f;
    float acc = 0.f;
    for (int i = threadIdx.x; i < B_ROWS; i += 1024) {
        float zp = (LOG2F(gsum_p[i]) + C2) * LN2;
        float zn = (LOG2F(gsum_n[i]) + C2) * LN2;
        float z  = zp + zn;
        float sp = fmaxf(z, 0.f) + log1pf(expf(-fabsf(z)));
        acc += sp;
    }
    red[threadIdx.x] = acc;
    __syncthreads();
    for (int s = 512; s > 0; s >>= 1) {
        if ((int)threadIdx.x < s) red[threadIdx.x] += red[threadIdx.x + s];
        __syncthreads();
    }
    if (threadIdx.x == 0) out[0] = red[0] / (float)B_ROWS;
}

extern "C" void kernel_launch(void* const* d_in, const int* in_sizes, int n_in,
                              void* d_out, int out_size, void* d_ws, size_t ws_size,
                              hipStream_t stream) {
    const float* text = (const float*)d_in[0];   // [B, D] f32
    const float* img  = (const float*)d_in[1];   // [N, D] f32
    const int* tlab   = (const int*)d_in[2];     // [B]
    const int* itgt   = (const int*)d_in[3];     // [N]
    float* out        = (float*)d_out;           // scalar f32

    char* ws = (char*)d_ws;
    unsigned short* Abf = (unsigned short*)(ws);                            // 4 MB
    unsigned short* Bbf = (unsigned short*)(ws + (size_t)B_ROWS * DIM * 2); // 4 MB
    float* gsum_p = (float*)(ws + (size_t)(B_ROWS + N_COLS) * DIM * 2);
    float* gsum_n = gsum_p + B_ROWS;

    // f32 -> bf16 conversions
    {
        int n4 = (B_ROWS * DIM) / 4;
        cvt_bf16_kernel<<<(n4 + 255) / 256, 256, 0, stream>>>(text, Abf, n4);
        n4 = (N_COLS * DIM) / 4;
        cvt_bf16_kernel<<<(n4 + 255) / 256, 256, 0, stream>>>(img, Bbf, n4);
    }

    // zero the partial-sum accumulators (graph-capturable async memset)
    hipMemsetAsync(gsum_p, 0, (size_t)(B_ROWS * 2) * sizeof(float), stream);

    dim3 grid(B_ROWS / (32 * WAVES), CSPLIT);
    fused_gemm_lse<<<grid, 256, 0, stream>>>(Abf, Bbf, tlab, itgt, gsum_p, gsum_n);

    finalize_kernel<<<1, 1024, 0, stream>>>(gsum_p, gsum_n, out);
}

// Round 4
// 473.339 us; speedup vs baseline: 1.0255x; 1.0255x over previous
//
#include <hip/hip_runtime.h>
#include <hip/hip_bf16.h>

// SupConLoss fused: logits = text @ image^T (bf16 MFMA), masked two-sided
// logsumexp with fixed shift, softplus-mean -> scalar.
// B = N = 8192, D = 256, NUM_CLASSES = 64, T = 1.
//
// R4 = R3 with the cvt_bt union syntax error fixed.
// R3: B is pre-transposed (cvt kernel) into the exact LDS chunk image so
// global_load_lds staging is lane-contiguous (R2's scattered staging caused
// 1.39 GB of L2-miss traffic). LDS read path + vmcnt(4) pipeline unchanged.

#define B_ROWS 8192
#define N_COLS 8192
#define DIM    256
#define CSPLIT 32                       // grid = (64, 32) = 2048 blocks
#define NTILES ((N_COLS / CSPLIT) / 32) // 8 col-tiles of 32 per block
#define WAVES  4                        // 4 waves x 32 rows = 128 rows/block

typedef __attribute__((ext_vector_type(8)))  short bf16x8;   // 8 bf16 = 4 VGPR
typedef __attribute__((ext_vector_type(16))) float f32x16;   // MFMA 32x32 acc

#if __has_builtin(__builtin_amdgcn_exp2f)
#define EXP2F(x) __builtin_amdgcn_exp2f(x)
#else
#define EXP2F(x) exp2f(x)
#endif
#if __has_builtin(__builtin_amdgcn_logf)
#define LOG2F(x) __builtin_amdgcn_logf(x)
#else
#define LOG2F(x) log2f(x)
#endif

__device__ __forceinline__ unsigned short f2bf(float f) {
    union { float f; unsigned u; } c; c.f = f;
    return (unsigned short)((c.u + 0x7FFFu + ((c.u >> 16) & 1u)) >> 16);
}

// f32 -> bf16 (RNE), 4 elements/thread, coalesced (for A = text features)
__global__ void cvt_bf16_kernel(const float* __restrict__ in,
                                unsigned short* __restrict__ out, int n4) {
    int i = blockIdx.x * blockDim.x + threadIdx.x;
    if (i >= n4) return;
    float4 v = reinterpret_cast<const float4*>(in)[i];
    ushort4 o;
    o.x = f2bf(v.x); o.y = f2bf(v.y); o.z = f2bf(v.z); o.w = f2bf(v.w);
    reinterpret_cast<ushort4*>(out)[i] = o;
}

// f32 -> bf16 + layout transform for B = image features.
// Output Bt: 256 groups (of 32 cols) x 16 KB. Within group g, chunk c (16 B)
// holds B[g*32 + (c&31)][k = (c>>5)*8 .. +8).  This is byte-for-byte the LDS
// tile image, so staging reads are fully lane-contiguous.
__global__ void cvt_bt_kernel(const float* __restrict__ img,
                              unsigned short* __restrict__ Bt) {
    int C = blockIdx.x * blockDim.x + threadIdx.x;   // global chunk id
    if (C >= (N_COLS / 32) * 1024) return;
    int g = C >> 10, c = C & 1023;
    int col = g * 32 + (c & 31);
    int k8  = c >> 5;
    const float4* src =
        reinterpret_cast<const float4*>(img + (size_t)col * DIM + k8 * 8);
    float4 v0 = src[0], v1 = src[1];
    unsigned short s[8];
    s[0] = f2bf(v0.x); s[1] = f2bf(v0.y); s[2] = f2bf(v0.z); s[3] = f2bf(v0.w);
    s[4] = f2bf(v1.x); s[5] = f2bf(v1.y); s[6] = f2bf(v1.z); s[7] = f2bf(v1.w);
    reinterpret_cast<bf16x8*>(Bt)[C] = *reinterpret_cast<const bf16x8*>(s);
}

// mfma_f32_32x32x16_bf16 layouts (HW-verified, absmax 0.0 in R1/R2):
//   A: row = lane&31, k = 8*(lane>>5)+j
//   B: col = lane&31, k = 8*(lane>>5)+j
//   C: col = lane&31, row = (r&3) + 8*(r>>2) + 4*(lane>>5)
__launch_bounds__(256, 3)
__global__ void fused_gemm_lse(const unsigned short* __restrict__ Abf,
                               const unsigned short* __restrict__ Bt,
                               const int* __restrict__ tlab,
                               const int* __restrict__ itgt,
                               float* __restrict__ gsum_p,
                               float* __restrict__ gsum_n) {
    __shared__ char lds[2 * 16384] __attribute__((aligned(128)));

    const int tid  = threadIdx.x;
    const int lane = tid & 63;
    const int wave = tid >> 6;
    const int half = lane >> 5;
    const int ln   = lane & 31;
    const int rb   = blockIdx.x * (32 * WAVES) + wave * 32;
    const int cb0  = blockIdx.y * (N_COLS / CSPLIT);

    // A fragments for all of K=256: 16 k-steps x 4 VGPR = 64 VGPR.
    bf16x8 afrag[16];
    const bf16x8* arow =
        reinterpret_cast<const bf16x8*>(Abf + (size_t)(rb + ln) * DIM) + half;
#pragma unroll
    for (int ks = 0; ks < 16; ++ks) afrag[ks] = arow[ks * 2];

    // Row classes for the 16 accumulator slots.
    int rowcls[16];
#pragma unroll
    for (int r = 0; r < 16; ++r)
        rowcls[r] = tlab[rb + (r & 3) + 8 * (r >> 2) + 4 * half];

    // Column classes for all NTILES tiles (hoisted so loop vmem = stage only).
    int colcls[NTILES];
#pragma unroll
    for (int t = 0; t < NTILES; ++t)
        colcls[t] = itgt[cb0 + t * 32 + ln];

    float sump[16], sumn[16];
#pragma unroll
    for (int r = 0; r < 16; ++r) { sump[r] = 0.f; sumn[r] = 0.f; }

    // Staging (lane-contiguous): tile t of this block is the 16 KB group
    // g = blockIdx.y*NTILES + t of Bt. Thread tid copies bytes
    // [tid*16 + i*4096, +16) for i in 0..3 -> each wave instr reads 1 KB
    // contiguous; LDS dest linear (chunk c at offset c*16).
    const char* bsrc = (const char*)Bt + (size_t)blockIdx.y * NTILES * 16384
                       + tid * 16;
    char* ldsd = lds + tid * 16;

#define STAGE(T, CUR) do {                                                   \
    const char* g_ = bsrc + (size_t)(T) * 16384;                             \
    char* l_ = ldsd + (CUR) * 16384;                                         \
    _Pragma("unroll")                                                        \
    for (int i_ = 0; i_ < 4; ++i_)                                           \
        __builtin_amdgcn_global_load_lds(                                    \
            (const __attribute__((address_space(1))) unsigned int*)(g_ + i_ * 4096), \
            (__attribute__((address_space(3))) unsigned int*)(l_ + i_ * 4096),      \
            16, 0, 0);                                                       \
} while (0)

    const float L2E = 1.4426950408889634f;  // log2(e)
    const float C2  = 72.0f;                // fixed shift in log2 domain

    STAGE(0, 0);
    asm volatile("" ::: "memory");  // keep prologue loads before the loop

#pragma unroll
    for (int t = 0; t < NTILES; ++t) {
        if (t + 1 < NTILES) {
            STAGE(t + 1, (t + 1) & 1);
            // wait current tile's 4 stage loads; keep next tile's 4 in flight
            asm volatile("s_waitcnt vmcnt(4)" ::: "memory");
        } else {
            asm volatile("s_waitcnt vmcnt(0)" ::: "memory");
        }
        __builtin_amdgcn_s_barrier();      // buf[t&1] fully staged by all
        asm volatile("" ::: "memory");

        const char* bbuf = lds + (t & 1) * 16384 + half * 512 + ln * 16;
        f32x16 acc;
#pragma unroll
        for (int r = 0; r < 16; ++r) acc[r] = 0.f;
#pragma unroll
        for (int ks = 0; ks < 16; ++ks) {
            bf16x8 bfrag = *reinterpret_cast<const bf16x8*>(bbuf + ks * 1024);
            acc = __builtin_amdgcn_mfma_f32_32x32x16_bf16(afrag[ks], bfrag, acc,
                                                          0, 0, 0);
        }

        __builtin_amdgcn_s_barrier();      // all waves done reading buf[t&1]
        asm volatile("" ::: "memory");

        // Epilogue VALU: overlaps the in-flight stage of tile t+1.
        const int cc = colcls[t];
#pragma unroll
        for (int r = 0; r < 16; ++r) {
            const float x  = acc[r];
            const bool pos = (rowcls[r] == cc);
            const float e  = EXP2F(__builtin_fmaf(x, pos ? -L2E : L2E, -C2));
            sump[r] += pos ? e : 0.f;
            sumn[r] += pos ? 0.f : e;
        }
    }
#undef STAGE

    // Reduce each row-sum across the 32 lanes of the half-wave, then atomics.
#pragma unroll
    for (int r = 0; r < 16; ++r) {
        float vp = sump[r], vn = sumn[r];
#pragma unroll
        for (int m = 1; m < 32; m <<= 1) {
            vp += __shfl_xor(vp, m, 64);
            vn += __shfl_xor(vn, m, 64);
        }
        if (ln == 0) {
            int row = rb + (r & 3) + 8 * (r >> 2) + 4 * half;
            atomicAdd(&gsum_p[row], vp);
            atomicAdd(&gsum_n[row], vn);
        }
    }
}

// lse_{p,n} = (log2(S) + C2) * ln2 ; loss = mean softplus(lse_p + lse_n)
__global__ void finalize_kernel(const float* __restrict__ gsum_p,
                                const float* __restrict__ gsum_n,
                                float* __restrict__ out) {
    __shared__ float red[1024];
    const float LN2 = 0.6931471805599453f;
    const float C2  = 72.0f;
    float acc = 0.f;
    for (int i = threadIdx.x; i < B_ROWS; i += 1024) {
        float zp = (LOG2F(gsum_p[i]) + C2) * LN2;
        float zn = (LOG2F(gsum_n[i]) + C2) * LN2;
        float z  = zp + zn;
        float sp = fmaxf(z, 0.f) + log1pf(expf(-fabsf(z)));
        acc += sp;
    }
    red[threadIdx.x] = acc;
    __syncthreads();
    for (int s = 512; s > 0; s >>= 1) {
        if ((int)threadIdx.x < s) red[threadIdx.x] += red[threadIdx.x + s];
        __syncthreads();
    }
    if (threadIdx.x == 0) out[0] = red[0] / (float)B_ROWS;
}

extern "C" void kernel_launch(void* const* d_in, const int* in_sizes, int n_in,
                              void* d_out, int out_size, void* d_ws, size_t ws_size,
                              hipStream_t stream) {
    const float* text = (const float*)d_in[0];   // [B, D] f32
    const float* img  = (const float*)d_in[1];   // [N, D] f32
    const int* tlab   = (const int*)d_in[2];     // [B]
    const int* itgt   = (const int*)d_in[3];     // [N]
    float* out        = (float*)d_out;           // scalar f32

    char* ws = (char*)d_ws;
    unsigned short* Abf = (unsigned short*)(ws);                            // 4 MB
    unsigned short* Bt  = (unsigned short*)(ws + (size_t)B_ROWS * DIM * 2); // 4 MB
    float* gsum_p = (float*)(ws + (size_t)(B_ROWS + N_COLS) * DIM * 2);
    float* gsum_n = gsum_p + B_ROWS;

    // f32 -> bf16 conversions (A coalesced; B transposed into LDS image)
    {
        int n4 = (B_ROWS * DIM) / 4;
        cvt_bf16_kernel<<<(n4 + 255) / 256, 256, 0, stream>>>(text, Abf, n4);
        int nc = (N_COLS / 32) * 1024;
        cvt_bt_kernel<<<(nc + 255) / 256, 256, 0, stream>>>(img, Bt);
    }

    // zero the partial-sum accumulators (graph-capturable async memset)
    hipMemsetAsync(gsum_p, 0, (size_t)(B_ROWS * 2) * sizeof(float), stream);

    dim3 grid(B_ROWS / (32 * WAVES), CSPLIT);
    fused_gemm_lse<<<grid, 256, 0, stream>>>(Abf, Bt, tlab, itgt, gsum_p, gsum_n);

    finalize_kernel<<<1, 1024, 0, stream>>>(gsum_p, gsum_n, out);
}

// Round 5
// 74.213 us; speedup vs baseline: 6.5410x; 6.3781x over previous
//
#include <hip/hip_runtime.h>
#include <hip/hip_bf16.h>

// SupConLoss fused: logits = text @ image^T (bf16 MFMA), masked two-sided
// logsumexp with fixed shift, softplus-mean -> scalar.
// B = N = 8192, D = 256, NUM_CLASSES = 64, T = 1.
//
// R5: R4's 470us was scratch-spill-bound (WRITE_SIZE 323MB, VGPR_Count 84 <<
// ~150 live). Restructured on 16x16x32 MFMA (afrag 32 VGPR not 64), 8 waves x
// 16 rows, single-buffer LDS + __syncthreads (m97 structure, no inline asm).

#define B_ROWS   8192
#define N_COLS   8192
#define DIM      256
#define CSPLIT   32                        // grid = (64, 32) = 2048 blocks
#define NTILES   ((N_COLS / CSPLIT) / 32)  // 8 col-tiles of 32 per block
#define BLK_ROWS 128                       // 8 waves x 16 rows
#define THREADS  512

typedef __attribute__((ext_vector_type(8))) short bf16x8;  // 8 bf16 = 4 VGPR
typedef __attribute__((ext_vector_type(4))) float f32x4;   // 16x16 MFMA acc

#if __has_builtin(__builtin_amdgcn_exp2f)
#define EXP2F(x) __builtin_amdgcn_exp2f(x)
#else
#define EXP2F(x) exp2f(x)
#endif
#if __has_builtin(__builtin_amdgcn_logf)
#define LOG2F(x) __builtin_amdgcn_logf(x)
#else
#define LOG2F(x) log2f(x)
#endif

__device__ __forceinline__ unsigned short f2bf(float f) {
    union { float f; unsigned u; } c; c.f = f;
    return (unsigned short)((c.u + 0x7FFFu + ((c.u >> 16) & 1u)) >> 16);
}

// f32 -> bf16 (RNE), 4 elements/thread, coalesced (for A = text features)
__global__ void cvt_bf16_kernel(const float* __restrict__ in,
                                unsigned short* __restrict__ out, int n4) {
    int i = blockIdx.x * blockDim.x + threadIdx.x;
    if (i >= n4) return;
    float4 v = reinterpret_cast<const float4*>(in)[i];
    ushort4 o;
    o.x = f2bf(v.x); o.y = f2bf(v.y); o.z = f2bf(v.z); o.w = f2bf(v.w);
    reinterpret_cast<ushort4*>(out)[i] = o;
}

// f32 -> bf16 + layout transform for B = image features.
// Bt: 256 groups (of 32 cols) x 16 KB. Within group g, chunk c (16 B) holds
// B[g*32 + (c&31)][k = (c>>5)*8 .. +8) -- byte-for-byte the LDS tile image.
__global__ void cvt_bt_kernel(const float* __restrict__ img,
                              unsigned short* __restrict__ Bt) {
    int C = blockIdx.x * blockDim.x + threadIdx.x;   // global chunk id
    if (C >= (N_COLS / 32) * 1024) return;
    int g = C >> 10, c = C & 1023;
    int col = g * 32 + (c & 31);
    int k8  = c >> 5;
    const float4* src =
        reinterpret_cast<const float4*>(img + (size_t)col * DIM + k8 * 8);
    float4 v0 = src[0], v1 = src[1];
    unsigned short s[8];
    s[0] = f2bf(v0.x); s[1] = f2bf(v0.y); s[2] = f2bf(v0.z); s[3] = f2bf(v0.w);
    s[4] = f2bf(v1.x); s[5] = f2bf(v1.y); s[6] = f2bf(v1.z); s[7] = f2bf(v1.w);
    reinterpret_cast<bf16x8*>(Bt)[C] = *reinterpret_cast<const bf16x8*>(s);
}

// mfma_f32_16x16x32_bf16 layouts:
//   A: row = lane&15, k = 8*(lane>>4)+j
//   B: col = lane&15, k = 8*(lane>>4)+j
//   C: col = lane&15, row = (lane>>4)*4 + j      (m89-verified)
// LDS tile (16 KB): chunk c=(k8*32+col) at byte c*16, k8 in [0,32), col [0,32).
// Read addr: k8 = ks*4 + (lane>>4), col = ct*16 + (lane&15)
//   -> byte = ks*2048 + (lane>>4)*512 + ct*256 + (lane&15)*16.
__launch_bounds__(THREADS, 4)
__global__ void fused_gemm_lse(const unsigned short* __restrict__ Abf,
                               const unsigned short* __restrict__ Bt,
                               const int* __restrict__ tlab,
                               const int* __restrict__ itgt,
                               float* __restrict__ gsum_p,
                               float* __restrict__ gsum_n) {
    __shared__ char lds[16384] __attribute__((aligned(128)));

    const int tid  = threadIdx.x;
    const int lane = tid & 63;
    const int wave = tid >> 6;
    const int l15  = lane & 15;
    const int q    = lane >> 4;                  // quarter-wave (k-group)
    const int rb   = blockIdx.x * BLK_ROWS + wave * 16;
    const int cb0  = blockIdx.y * (N_COLS / CSPLIT);

    // A fragments for all of K=256: 8 k-steps x 4 VGPR = 32 VGPR.
    bf16x8 afrag[8];
    const bf16x8* arow =
        reinterpret_cast<const bf16x8*>(Abf + (size_t)(rb + l15) * DIM) + q;
#pragma unroll
    for (int ks = 0; ks < 8; ++ks) afrag[ks] = arow[ks * 4];

    // Row classes of this thread's 4 accumulator rows.
    int rowcls[4];
#pragma unroll
    for (int j = 0; j < 4; ++j) rowcls[j] = tlab[rb + q * 4 + j];

    float sump[4] = {0.f, 0.f, 0.f, 0.f};
    float sumn[4] = {0.f, 0.f, 0.f, 0.f};

    // Staging: thread copies chunks tid and tid+512 (16 B each) -> 16 KB/tile.
    // Per wave: 1 KB contiguous global read; LDS dest linear (m97 rule).
    const char* bsrc = (const char*)Bt
        + ((size_t)blockIdx.y * NTILES) * 16384 + tid * 16;
    char* ldsd = lds + tid * 16;

    const float L2E = 1.4426950408889634f;  // log2(e)
    const float C2  = 72.0f;                // fixed shift in log2 domain

    for (int t = 0; t < NTILES; ++t) {
#pragma unroll
        for (int i = 0; i < 2; ++i)
            __builtin_amdgcn_global_load_lds(
                (const __attribute__((address_space(1))) unsigned int*)
                    (bsrc + (size_t)t * 16384 + i * 8192),
                (__attribute__((address_space(3))) unsigned int*)
                    (ldsd + i * 8192),
                16, 0, 0);
        const int cc0 = itgt[cb0 + t * 32 + l15];
        const int cc1 = itgt[cb0 + t * 32 + 16 + l15];
        __syncthreads();   // drains vmcnt -> tile staged for all waves

        f32x4 acc0 = {0.f, 0.f, 0.f, 0.f};
        f32x4 acc1 = {0.f, 0.f, 0.f, 0.f};
        const char* bb = lds + q * 512 + l15 * 16;
#pragma unroll
        for (int ks = 0; ks < 8; ++ks) {
            bf16x8 b0 = *reinterpret_cast<const bf16x8*>(bb + ks * 2048);
            bf16x8 b1 = *reinterpret_cast<const bf16x8*>(bb + ks * 2048 + 256);
            acc0 = __builtin_amdgcn_mfma_f32_16x16x32_bf16(afrag[ks], b0, acc0,
                                                           0, 0, 0);
            acc1 = __builtin_amdgcn_mfma_f32_16x16x32_bf16(afrag[ks], b1, acc1,
                                                           0, 0, 0);
        }
        __syncthreads();   // all waves done reading before next stage

        // Epilogue (registers only): route exp(+/-x - C) to pos/neg sums.
#pragma unroll
        for (int j = 0; j < 4; ++j) {
            const float x0 = acc0[j];
            const bool  p0 = (rowcls[j] == cc0);
            const float e0 = EXP2F(__builtin_fmaf(x0, p0 ? -L2E : L2E, -C2));
            sump[j] += p0 ? e0 : 0.f;
            sumn[j] += p0 ? 0.f : e0;
            const float x1 = acc1[j];
            const bool  p1 = (rowcls[j] == cc1);
            const float e1 = EXP2F(__builtin_fmaf(x1, p1 ? -L2E : L2E, -C2));
            sump[j] += p1 ? e1 : 0.f;
            sumn[j] += p1 ? 0.f : e1;
        }
    }

    // Reduce over the 16 cols of each quarter-wave, then one atomic per row.
#pragma unroll
    for (int j = 0; j < 4; ++j) {
        float vp = sump[j], vn = sumn[j];
#pragma unroll
        for (int m = 1; m < 16; m <<= 1) {
            vp += __shfl_xor(vp, m, 64);
            vn += __shfl_xor(vn, m, 64);
        }
        if (l15 == 0) {
            const int row = rb + q * 4 + j;
            atomicAdd(&gsum_p[row], vp);
            atomicAdd(&gsum_n[row], vn);
        }
    }
}

// lse_{p,n} = (log2(S) + C2) * ln2 ; loss = mean softplus(lse_p + lse_n)
__global__ void finalize_kernel(const float* __restrict__ gsum_p,
                                const float* __restrict__ gsum_n,
                                float* __restrict__ out) {
    __shared__ float red[1024];
    const float LN2 = 0.6931471805599453f;
    const float C2  = 72.0f;
    float acc = 0.f;
    for (int i = threadIdx.x; i < B_ROWS; i += 1024) {
        float zp = (LOG2F(gsum_p[i]) + C2) * LN2;
        float zn = (LOG2F(gsum_n[i]) + C2) * LN2;
        float z  = zp + zn;
        float sp = fmaxf(z, 0.f) + log1pf(expf(-fabsf(z)));
        acc += sp;
    }
    red[threadIdx.x] = acc;
    __syncthreads();
    for (int s = 512; s > 0; s >>= 1) {
        if ((int)threadIdx.x < s) red[threadIdx.x] += red[threadIdx.x + s];
        __syncthreads();
    }
    if (threadIdx.x == 0) out[0] = red[0] / (float)B_ROWS;
}

extern "C" void kernel_launch(void* const* d_in, const int* in_sizes, int n_in,
                              void* d_out, int out_size, void* d_ws, size_t ws_size,
                              hipStream_t stream) {
    const float* text = (const float*)d_in[0];   // [B, D] f32
    const float* img  = (const float*)d_in[1];   // [N, D] f32
    const int* tlab   = (const int*)d_in[2];     // [B]
    const int* itgt   = (const int*)d_in[3];     // [N]
    float* out        = (float*)d_out;           // scalar f32

    char* ws = (char*)d_ws;
    unsigned short* Abf = (unsigned short*)(ws);                            // 4 MB
    unsigned short* Bt  = (unsigned short*)(ws + (size_t)B_ROWS * DIM * 2); // 4 MB
    float* gsum_p = (float*)(ws + (size_t)(B_ROWS + N_COLS) * DIM * 2);
    float* gsum_n = gsum_p + B_ROWS;

    // f32 -> bf16 conversions (A coalesced; B transposed into LDS image)
    {
        int n4 = (B_ROWS * DIM) / 4;
        cvt_bf16_kernel<<<(n4 + 255) / 256, 256, 0, stream>>>(text, Abf, n4);
        int nc = (N_COLS / 32) * 1024;
        cvt_bt_kernel<<<(nc + 255) / 256, 256, 0, stream>>>(img, Bt);
    }

    // zero the partial-sum accumulators (graph-capturable async memset)
    hipMemsetAsync(gsum_p, 0, (size_t)(B_ROWS * 2) * sizeof(float), stream);

    dim3 grid(B_ROWS / BLK_ROWS, CSPLIT);
    fused_gemm_lse<<<grid, THREADS, 0, stream>>>(Abf, Bt, tlab, itgt,
                                                 gsum_p, gsum_n);

    finalize_kernel<<<1, 1024, 0, stream>>>(gsum_p, gsum_n, out);
}

// Round 6
// 70.950 us; speedup vs baseline: 6.8419x; 1.0460x over previous
//
#include <hip/hip_runtime.h>
#include <hip/hip_bf16.h>

// SupConLoss fused: logits = text @ image^T (bf16 MFMA), masked two-sided
// logsumexp with fixed shift, softplus-mean -> scalar.
// B = N = 8192, D = 256, NUM_CLASSES = 64, T = 1.
//
// R6: R5 + double-buffered LDS with counted s_waitcnt vmcnt(2) prefetch
// (T3/T4 minimum pipeline) to remove the per-tile barrier-drain stall that
// capped R5 at MfmaUtil 25%. Also fused the two cvt kernels + gsum zeroing
// into one dispatch. Register budget is small (~80 live), so the counted-
// vmcnt asm is safe now (R2's spill disaster had ~150 live + cap 3).

#define B_ROWS   8192
#define N_COLS   8192
#define DIM      256
#define CSPLIT   32                        // grid = (64, 32) = 2048 blocks
#define NTILES   ((N_COLS / CSPLIT) / 32)  // 8 col-tiles of 32 per block
#define BLK_ROWS 128                       // 8 waves x 16 rows
#define THREADS  512

typedef __attribute__((ext_vector_type(8))) short bf16x8;  // 8 bf16 = 4 VGPR
typedef __attribute__((ext_vector_type(4))) float f32x4;   // 16x16 MFMA acc

#if __has_builtin(__builtin_amdgcn_exp2f)
#define EXP2F(x) __builtin_amdgcn_exp2f(x)
#else
#define EXP2F(x) exp2f(x)
#endif
#if __has_builtin(__builtin_amdgcn_logf)
#define LOG2F(x) __builtin_amdgcn_logf(x)
#else
#define LOG2F(x) log2f(x)
#endif

__device__ __forceinline__ unsigned short f2bf(float f) {
    union { float f; unsigned u; } c; c.f = f;
    return (unsigned short)((c.u + 0x7FFFu + ((c.u >> 16) & 1u)) >> 16);
}

// One dispatch: zero gsum (16K floats), cvt A (row-major bf16), cvt+transpose
// B into Bt (the LDS chunk image).
// Bt: 256 groups (of 32 cols) x 16 KB. Within group g, chunk c (16 B) holds
// B[g*32 + (c&31)][k = (c>>5)*8 .. +8).
__global__ void cvt_all_kernel(const float* __restrict__ text,
                               const float* __restrict__ img,
                               unsigned short* __restrict__ Abf,
                               unsigned short* __restrict__ Bt,
                               float* __restrict__ gsum) {
    const int i = blockIdx.x * blockDim.x + threadIdx.x;   // [0, 524288)
    if (i < 4096) {   // 16384 floats = gsum_p[8192] ++ gsum_n[8192]
        reinterpret_cast<float4*>(gsum)[i] = float4{0.f, 0.f, 0.f, 0.f};
    }
    if (i < 262144) {
        // A: 8 consecutive f32 -> 8 bf16, coalesced
        const float4* src = reinterpret_cast<const float4*>(text) + i * 2;
        float4 v0 = src[0], v1 = src[1];
        unsigned short s[8];
        s[0] = f2bf(v0.x); s[1] = f2bf(v0.y); s[2] = f2bf(v0.z); s[3] = f2bf(v0.w);
        s[4] = f2bf(v1.x); s[5] = f2bf(v1.y); s[6] = f2bf(v1.z); s[7] = f2bf(v1.w);
        reinterpret_cast<bf16x8*>(Abf)[i] = *reinterpret_cast<const bf16x8*>(s);
    } else {
        const int C = i - 262144;           // Bt chunk id, [0, 262144)
        const int g = C >> 10, c = C & 1023;
        const int col = g * 32 + (c & 31);
        const int k8  = c >> 5;
        const float4* src =
            reinterpret_cast<const float4*>(img + (size_t)col * DIM + k8 * 8);
        float4 v0 = src[0], v1 = src[1];
        unsigned short s[8];
        s[0] = f2bf(v0.x); s[1] = f2bf(v0.y); s[2] = f2bf(v0.z); s[3] = f2bf(v0.w);
        s[4] = f2bf(v1.x); s[5] = f2bf(v1.y); s[6] = f2bf(v1.z); s[7] = f2bf(v1.w);
        reinterpret_cast<bf16x8*>(Bt)[C] = *reinterpret_cast<const bf16x8*>(s);
    }
}

// mfma_f32_16x16x32_bf16 layouts (R5-verified, absmax 0.0):
//   A: row = lane&15, k = 8*(lane>>4)+j
//   B: col = lane&15, k = 8*(lane>>4)+j
//   C: col = lane&15, row = (lane>>4)*4 + j
// LDS tile (16 KB): chunk c=(k8*32+col) at byte c*16.
// Pipeline per tile: STAGE(t+1) -> vmcnt(2) -> barrier -> ds_read+MFMA ->
// sched_barrier -> barrier -> epilogue (overlaps t+1's in-flight loads).
__launch_bounds__(THREADS, 4)
__global__ void fused_gemm_lse(const unsigned short* __restrict__ Abf,
                               const unsigned short* __restrict__ Bt,
                               const int* __restrict__ tlab,
                               const int* __restrict__ itgt,
                               float* __restrict__ gsum_p,
                               float* __restrict__ gsum_n) {
    __shared__ char lds[2 * 16384] __attribute__((aligned(128)));

    const int tid  = threadIdx.x;
    const int lane = tid & 63;
    const int wave = tid >> 6;
    const int l15  = lane & 15;
    const int q    = lane >> 4;                  // quarter-wave (k-group)
    const int rb   = blockIdx.x * BLK_ROWS + wave * 16;
    const int cb0  = blockIdx.y * (N_COLS / CSPLIT);

    // A fragments for all of K=256: 8 k-steps x 4 VGPR = 32 VGPR.
    bf16x8 afrag[8];
    const bf16x8* arow =
        reinterpret_cast<const bf16x8*>(Abf + (size_t)(rb + l15) * DIM) + q;
#pragma unroll
    for (int ks = 0; ks < 8; ++ks) afrag[ks] = arow[ks * 4];

    // Row classes of this thread's 4 accumulator rows.
    int rowcls[4];
#pragma unroll
    for (int j = 0; j < 4; ++j) rowcls[j] = tlab[rb + q * 4 + j];

    // Column classes for ALL tiles, hoisted so in-loop VMEM = stage loads
    // only (keeps the vmcnt count exact).
    int ccls0[NTILES], ccls1[NTILES];
#pragma unroll
    for (int t = 0; t < NTILES; ++t) {
        ccls0[t] = itgt[cb0 + t * 32 + l15];
        ccls1[t] = itgt[cb0 + t * 32 + 16 + l15];
    }

    float sump[4] = {0.f, 0.f, 0.f, 0.f};
    float sumn[4] = {0.f, 0.f, 0.f, 0.f};

    // Staging: thread copies chunks tid and tid+512 (16 B each) per tile.
    const char* bsrc = (const char*)Bt
        + ((size_t)blockIdx.y * NTILES) * 16384 + tid * 16;
    char* ldsd = lds + tid * 16;

#define STAGE(T, BUF) do {                                                    \
    _Pragma("unroll")                                                         \
    for (int i_ = 0; i_ < 2; ++i_)                                            \
        __builtin_amdgcn_global_load_lds(                                     \
            (const __attribute__((address_space(1))) unsigned int*)           \
                (bsrc + (size_t)(T) * 16384 + i_ * 8192),                     \
            (__attribute__((address_space(3))) unsigned int*)                 \
                (ldsd + (BUF) * 16384 + i_ * 8192),                           \
            16, 0, 0);                                                        \
} while (0)

    const float L2E = 1.4426950408889634f;  // log2(e)
    const float C2  = 72.0f;                // fixed shift in log2 domain

    STAGE(0, 0);

#pragma unroll
    for (int t = 0; t < NTILES; ++t) {
        if (t + 1 < NTILES) {
            STAGE(t + 1, (t + 1) & 1);
            // wait tile t's 2 loads; keep tile t+1's 2 in flight
            asm volatile("s_waitcnt vmcnt(2)" ::: "memory");
        } else {
            asm volatile("s_waitcnt vmcnt(0)" ::: "memory");
        }
        __builtin_amdgcn_s_barrier();          // tile t staged by all waves
        __builtin_amdgcn_sched_barrier(0);     // no ds_read hoist above

        f32x4 acc0 = {0.f, 0.f, 0.f, 0.f};
        f32x4 acc1 = {0.f, 0.f, 0.f, 0.f};
        const char* bb = lds + (t & 1) * 16384 + q * 512 + l15 * 16;
#pragma unroll
        for (int ks = 0; ks < 8; ++ks) {
            bf16x8 b0 = *reinterpret_cast<const bf16x8*>(bb + ks * 2048);
            bf16x8 b1 = *reinterpret_cast<const bf16x8*>(bb + ks * 2048 + 256);
            acc0 = __builtin_amdgcn_mfma_f32_16x16x32_bf16(afrag[ks], b0, acc0,
                                                           0, 0, 0);
            acc1 = __builtin_amdgcn_mfma_f32_16x16x32_bf16(afrag[ks], b1, acc1,
                                                           0, 0, 0);
        }
        __builtin_amdgcn_sched_barrier(0);     // no ds_read sink below
        __builtin_amdgcn_s_barrier();          // all done reading buf[t&1]

        // Epilogue (registers only): overlaps tile t+1's in-flight loads.
        const int cc0 = ccls0[t], cc1 = ccls1[t];
#pragma unroll
        for (int j = 0; j < 4; ++j) {
            const float x0 = acc0[j];
            const bool  p0 = (rowcls[j] == cc0);
            const float e0 = EXP2F(__builtin_fmaf(x0, p0 ? -L2E : L2E, -C2));
            sump[j] += p0 ? e0 : 0.f;
            sumn[j] += p0 ? 0.f : e0;
            const float x1 = acc1[j];
            const bool  p1 = (rowcls[j] == cc1);
            const float e1 = EXP2F(__builtin_fmaf(x1, p1 ? -L2E : L2E, -C2));
            sump[j] += p1 ? e1 : 0.f;
            sumn[j] += p1 ? 0.f : e1;
        }
    }
#undef STAGE

    // Reduce over the 16 cols of each quarter-wave, then one atomic per row.
#pragma unroll
    for (int j = 0; j < 4; ++j) {
        float vp = sump[j], vn = sumn[j];
#pragma unroll
        for (int m = 1; m < 16; m <<= 1) {
            vp += __shfl_xor(vp, m, 64);
            vn += __shfl_xor(vn, m, 64);
        }
        if (l15 == 0) {
            const int row = rb + q * 4 + j;
            atomicAdd(&gsum_p[row], vp);
            atomicAdd(&gsum_n[row], vn);
        }
    }
}

// lse_{p,n} = (log2(S) + C2) * ln2 ; loss = mean softplus(lse_p + lse_n)
__global__ void finalize_kernel(const float* __restrict__ gsum_p,
                                const float* __restrict__ gsum_n,
                                float* __restrict__ out) {
    __shared__ float red[1024];
    const float LN2 = 0.6931471805599453f;
    const float C2  = 72.0f;
    float acc = 0.f;
    for (int i = threadIdx.x; i < B_ROWS; i += 1024) {
        float zp = (LOG2F(gsum_p[i]) + C2) * LN2;
        float zn = (LOG2F(gsum_n[i]) + C2) * LN2;
        float z  = zp + zn;
        float sp = fmaxf(z, 0.f) + log1pf(expf(-fabsf(z)));
        acc += sp;
    }
    red[threadIdx.x] = acc;
    __syncthreads();
    for (int s = 512; s > 0; s >>= 1) {
        if ((int)threadIdx.x < s) red[threadIdx.x] += red[threadIdx.x + s];
        __syncthreads();
    }
    if (threadIdx.x == 0) out[0] = red[0] / (float)B_ROWS;
}

extern "C" void kernel_launch(void* const* d_in, const int* in_sizes, int n_in,
                              void* d_out, int out_size, void* d_ws, size_t ws_size,
                              hipStream_t stream) {
    const float* text = (const float*)d_in[0];   // [B, D] f32
    const float* img  = (const float*)d_in[1];   // [N, D] f32
    const int* tlab   = (const int*)d_in[2];     // [B]
    const int* itgt   = (const int*)d_in[3];     // [N]
    float* out        = (float*)d_out;           // scalar f32

    char* ws = (char*)d_ws;
    unsigned short* Abf = (unsigned short*)(ws);                            // 4 MB
    unsigned short* Bt  = (unsigned short*)(ws + (size_t)B_ROWS * DIM * 2); // 4 MB
    float* gsum_p = (float*)(ws + (size_t)(B_ROWS + N_COLS) * DIM * 2);
    float* gsum_n = gsum_p + B_ROWS;

    // One dispatch: zero gsum + cvt A + cvt/transpose B.
    cvt_all_kernel<<<(2 * 262144) / 256, 256, 0, stream>>>(text, img, Abf, Bt,
                                                           gsum_p);

    dim3 grid(B_ROWS / BLK_ROWS, CSPLIT);
    fused_gemm_lse<<<grid, THREADS, 0, stream>>>(Abf, Bt, tlab, itgt,
                                                 gsum_p, gsum_n);

    finalize_kernel<<<1, 1024, 0, stream>>>(gsum_p, gsum_n, out);
}

// Round 7
// 67.498 us; speedup vs baseline: 7.1917x; 1.0511x over previous
//
#include <hip/hip_runtime.h>
#include <hip/hip_bf16.h>

// SupConLoss fused: logits = text @ image^T (bf16 MFMA), masked two-sided
// logsumexp with fixed shift, softplus-mean -> scalar.
// B = N = 8192, D = 256, NUM_CLASSES = 64, T = 1.
//
// R7: R5 structure (single-buffer LDS + __syncthreads, no inline asm) with
// 2 row-tiles per wave (32 rows): each LDS B-fragment read now feeds 4 MFMAs
// instead of 1, halving the LDS-read traffic that bound R5 (~41us of 56.6).
// R6's counted-vmcnt double-buffer regressed (occupancy 54->34%) - reverted.
// Stage(t+1) issues before the epilogue so exp2/VALU overlap load flight.

#define B_ROWS   8192
#define N_COLS   8192
#define DIM      256
#define CSPLIT   32                        // grid = (32, 32) = 1024 blocks
#define NTILES   ((N_COLS / CSPLIT) / 32)  // 8 col-tiles of 32 per block
#define BLK_ROWS 256                       // 8 waves x 32 rows
#define THREADS  512

typedef __attribute__((ext_vector_type(8))) short bf16x8;  // 8 bf16 = 4 VGPR
typedef __attribute__((ext_vector_type(4))) float f32x4;   // 16x16 MFMA acc

#if __has_builtin(__builtin_amdgcn_exp2f)
#define EXP2F(x) __builtin_amdgcn_exp2f(x)
#else
#define EXP2F(x) exp2f(x)
#endif
#if __has_builtin(__builtin_amdgcn_logf)
#define LOG2F(x) __builtin_amdgcn_logf(x)
#else
#define LOG2F(x) log2f(x)
#endif

__device__ __forceinline__ unsigned short f2bf(float f) {
    union { float f; unsigned u; } c; c.f = f;
    return (unsigned short)((c.u + 0x7FFFu + ((c.u >> 16) & 1u)) >> 16);
}

// One dispatch: zero gsum (16K floats), cvt A (row-major bf16), cvt+transpose
// B into Bt (the LDS chunk image).
// Bt: 256 groups (of 32 cols) x 16 KB. Within group g, chunk c (16 B) holds
// B[g*32 + (c&31)][k = (c>>5)*8 .. +8).
__global__ void cvt_all_kernel(const float* __restrict__ text,
                               const float* __restrict__ img,
                               unsigned short* __restrict__ Abf,
                               unsigned short* __restrict__ Bt,
                               float* __restrict__ gsum) {
    const int i = blockIdx.x * blockDim.x + threadIdx.x;   // [0, 524288)
    if (i < 4096) {   // 16384 floats = gsum_p[8192] ++ gsum_n[8192]
        reinterpret_cast<float4*>(gsum)[i] = float4{0.f, 0.f, 0.f, 0.f};
    }
    if (i < 262144) {
        // A: 8 consecutive f32 -> 8 bf16, coalesced
        const float4* src = reinterpret_cast<const float4*>(text) + i * 2;
        float4 v0 = src[0], v1 = src[1];
        unsigned short s[8];
        s[0] = f2bf(v0.x); s[1] = f2bf(v0.y); s[2] = f2bf(v0.z); s[3] = f2bf(v0.w);
        s[4] = f2bf(v1.x); s[5] = f2bf(v1.y); s[6] = f2bf(v1.z); s[7] = f2bf(v1.w);
        reinterpret_cast<bf16x8*>(Abf)[i] = *reinterpret_cast<const bf16x8*>(s);
    } else {
        const int C = i - 262144;           // Bt chunk id, [0, 262144)
        const int g = C >> 10, c = C & 1023;
        const int col = g * 32 + (c & 31);
        const int k8  = c >> 5;
        const float4* src =
            reinterpret_cast<const float4*>(img + (size_t)col * DIM + k8 * 8);
        float4 v0 = src[0], v1 = src[1];
        unsigned short s[8];
        s[0] = f2bf(v0.x); s[1] = f2bf(v0.y); s[2] = f2bf(v0.z); s[3] = f2bf(v0.w);
        s[4] = f2bf(v1.x); s[5] = f2bf(v1.y); s[6] = f2bf(v1.z); s[7] = f2bf(v1.w);
        reinterpret_cast<bf16x8*>(Bt)[C] = *reinterpret_cast<const bf16x8*>(s);
    }
}

// mfma_f32_16x16x32_bf16 layouts (R5-verified, absmax 0.0):
//   A: row = lane&15, k = 8*(lane>>4)+j
//   B: col = lane&15, k = 8*(lane>>4)+j
//   C: col = lane&15, row = (lane>>4)*4 + j
// LDS tile (16 KB): chunk c=(k8*32+col) at byte c*16.
// B-read addr: k8 = ks*4 + (lane>>4), col = ct*16 + (lane&15)
//   -> byte = ks*2048 + (lane>>4)*512 + ct*256 + (lane&15)*16.
__launch_bounds__(THREADS, 2)
__global__ void fused_gemm_lse(const unsigned short* __restrict__ Abf,
                               const unsigned short* __restrict__ Bt,
                               const int* __restrict__ tlab,
                               const int* __restrict__ itgt,
                               float* __restrict__ gsum_p,
                               float* __restrict__ gsum_n) {
    __shared__ char lds[16384] __attribute__((aligned(128)));

    const int tid  = threadIdx.x;
    const int lane = tid & 63;
    const int wave = tid >> 6;
    const int l15  = lane & 15;
    const int q    = lane >> 4;                  // quarter-wave (k-group)
    const int rb   = blockIdx.x * BLK_ROWS + wave * 32;  // 2 row-tiles
    const int cb0  = blockIdx.y * (N_COLS / CSPLIT);

    // A fragments for both row-tiles, all of K=256: 2 x 8 x 4 = 64 VGPR.
    bf16x8 afrag0[8], afrag1[8];
    const bf16x8* arow0 =
        reinterpret_cast<const bf16x8*>(Abf + (size_t)(rb + l15) * DIM) + q;
    const bf16x8* arow1 =
        reinterpret_cast<const bf16x8*>(Abf + (size_t)(rb + 16 + l15) * DIM) + q;
#pragma unroll
    for (int ks = 0; ks < 8; ++ks) {
        afrag0[ks] = arow0[ks * 4];
        afrag1[ks] = arow1[ks * 4];
    }

    // Row classes of this thread's accumulator rows (2 row-tiles x 4 rows).
    int rowcls0[4], rowcls1[4];
#pragma unroll
    for (int j = 0; j < 4; ++j) {
        rowcls0[j] = tlab[rb + q * 4 + j];
        rowcls1[j] = tlab[rb + 16 + q * 4 + j];
    }

    float sump0[4] = {0, 0, 0, 0}, sumn0[4] = {0, 0, 0, 0};
    float sump1[4] = {0, 0, 0, 0}, sumn1[4] = {0, 0, 0, 0};

    // Staging: thread copies chunks tid and tid+512 (16 B each) per tile.
    const char* bsrc = (const char*)Bt
        + ((size_t)blockIdx.y * NTILES) * 16384 + tid * 16;
    char* ldsd = lds + tid * 16;

#define STAGE(T) do {                                                         \
    _Pragma("unroll")                                                         \
    for (int i_ = 0; i_ < 2; ++i_)                                            \
        __builtin_amdgcn_global_load_lds(                                     \
            (const __attribute__((address_space(1))) unsigned int*)           \
                (bsrc + (size_t)(T) * 16384 + i_ * 8192),                     \
            (__attribute__((address_space(3))) unsigned int*)                 \
                (ldsd + i_ * 8192),                                           \
            16, 0, 0);                                                        \
} while (0)

    const float L2E = 1.4426950408889634f;  // log2(e)
    const float C2  = 72.0f;                // fixed shift in log2 domain

    STAGE(0);
    int cc0 = itgt[cb0 + l15];
    int cc1 = itgt[cb0 + 16 + l15];

    for (int t = 0; t < NTILES; ++t) {
        __syncthreads();   // drains vmcnt -> tile t staged for all waves

        f32x4 acc00 = {0, 0, 0, 0}, acc01 = {0, 0, 0, 0};
        f32x4 acc10 = {0, 0, 0, 0}, acc11 = {0, 0, 0, 0};
        const char* bb = lds + q * 512 + l15 * 16;
#pragma unroll
        for (int ks = 0; ks < 8; ++ks) {
            bf16x8 b0 = *reinterpret_cast<const bf16x8*>(bb + ks * 2048);
            bf16x8 b1 = *reinterpret_cast<const bf16x8*>(bb + ks * 2048 + 256);
            acc00 = __builtin_amdgcn_mfma_f32_16x16x32_bf16(afrag0[ks], b0,
                                                            acc00, 0, 0, 0);
            acc01 = __builtin_amdgcn_mfma_f32_16x16x32_bf16(afrag0[ks], b1,
                                                            acc01, 0, 0, 0);
            acc10 = __builtin_amdgcn_mfma_f32_16x16x32_bf16(afrag1[ks], b0,
                                                            acc10, 0, 0, 0);
            acc11 = __builtin_amdgcn_mfma_f32_16x16x32_bf16(afrag1[ks], b1,
                                                            acc11, 0, 0, 0);
        }
        __syncthreads();   // all waves done reading before restage

        // Issue next tile's stage loads first, then do the epilogue VALU
        // while they are in flight (next __syncthreads drains them).
        if (t + 1 < NTILES) STAGE(t + 1);

        const int ncc0 = (t + 1 < NTILES) ? itgt[cb0 + (t + 1) * 32 + l15] : 0;
        const int ncc1 = (t + 1 < NTILES) ? itgt[cb0 + (t + 1) * 32 + 16 + l15] : 0;

#pragma unroll
        for (int j = 0; j < 4; ++j) {
            {
                const float x = acc00[j];
                const bool  p = (rowcls0[j] == cc0);
                const float e = EXP2F(__builtin_fmaf(x, p ? -L2E : L2E, -C2));
                sump0[j] += p ? e : 0.f;
                sumn0[j] += p ? 0.f : e;
            }
            {
                const float x = acc01[j];
                const bool  p = (rowcls0[j] == cc1);
                const float e = EXP2F(__builtin_fmaf(x, p ? -L2E : L2E, -C2));
                sump0[j] += p ? e : 0.f;
                sumn0[j] += p ? 0.f : e;
            }
            {
                const float x = acc10[j];
                const bool  p = (rowcls1[j] == cc0);
                const float e = EXP2F(__builtin_fmaf(x, p ? -L2E : L2E, -C2));
                sump1[j] += p ? e : 0.f;
                sumn1[j] += p ? 0.f : e;
            }
            {
                const float x = acc11[j];
                const bool  p = (rowcls1[j] == cc1);
                const float e = EXP2F(__builtin_fmaf(x, p ? -L2E : L2E, -C2));
                sump1[j] += p ? e : 0.f;
                sumn1[j] += p ? 0.f : e;
            }
        }
        cc0 = ncc0;
        cc1 = ncc1;
    }
#undef STAGE

    // Reduce over the 16 cols of each quarter-wave, then one atomic per row.
#pragma unroll
    for (int j = 0; j < 4; ++j) {
        float vp0 = sump0[j], vn0 = sumn0[j];
        float vp1 = sump1[j], vn1 = sumn1[j];
#pragma unroll
        for (int m = 1; m < 16; m <<= 1) {
            vp0 += __shfl_xor(vp0, m, 64);
            vn0 += __shfl_xor(vn0, m, 64);
            vp1 += __shfl_xor(vp1, m, 64);
            vn1 += __shfl_xor(vn1, m, 64);
        }
        if (l15 == 0) {
            const int row0 = rb + q * 4 + j;
            atomicAdd(&gsum_p[row0], vp0);
            atomicAdd(&gsum_n[row0], vn0);
            const int row1 = rb + 16 + q * 4 + j;
            atomicAdd(&gsum_p[row1], vp1);
            atomicAdd(&gsum_n[row1], vn1);
        }
    }
}

// lse_{p,n} = (log2(S) + C2) * ln2 ; loss = mean softplus(lse_p + lse_n)
__global__ void finalize_kernel(const float* __restrict__ gsum_p,
                                const float* __restrict__ gsum_n,
                                float* __restrict__ out) {
    __shared__ float red[1024];
    const float LN2 = 0.6931471805599453f;
    const float C2  = 72.0f;
    float acc = 0.f;
    for (int i = threadIdx.x; i < B_ROWS; i += 1024) {
        float zp = (LOG2F(gsum_p[i]) + C2) * LN2;
        float zn = (LOG2F(gsum_n[i]) + C2) * LN2;
        float z  = zp + zn;
        float sp = fmaxf(z, 0.f) + log1pf(expf(-fabsf(z)));
        acc += sp;
    }
    red[threadIdx.x] = acc;
    __syncthreads();
    for (int s = 512; s > 0; s >>= 1) {
        if ((int)threadIdx.x < s) red[threadIdx.x] += red[threadIdx.x + s];
        __syncthreads();
    }
    if (threadIdx.x == 0) out[0] = red[0] / (float)B_ROWS;
}

extern "C" void kernel_launch(void* const* d_in, const int* in_sizes, int n_in,
                              void* d_out, int out_size, void* d_ws, size_t ws_size,
                              hipStream_t stream) {
    const float* text = (const float*)d_in[0];   // [B, D] f32
    const float* img  = (const float*)d_in[1];   // [N, D] f32
    const int* tlab   = (const int*)d_in[2];     // [B]
    const int* itgt   = (const int*)d_in[3];     // [N]
    float* out        = (float*)d_out;           // scalar f32

    char* ws = (char*)d_ws;
    unsigned short* Abf = (unsigned short*)(ws);                            // 4 MB
    unsigned short* Bt  = (unsigned short*)(ws + (size_t)B_ROWS * DIM * 2); // 4 MB
    float* gsum_p = (float*)(ws + (size_t)(B_ROWS + N_COLS) * DIM * 2);
    float* gsum_n = gsum_p + B_ROWS;

    // One dispatch: zero gsum + cvt A + cvt/transpose B.
    cvt_all_kernel<<<(2 * 262144) / 256, 256, 0, stream>>>(text, img, Abf, Bt,
                                                           gsum_p);

    dim3 grid(B_ROWS / BLK_ROWS, CSPLIT);
    fused_gemm_lse<<<grid, THREADS, 0, stream>>>(Abf, Bt, tlab, itgt,
                                                 gsum_p, gsum_n);

    finalize_kernel<<<1, 1024, 0, stream>>>(gsum_p, gsum_n, out);
}